// Round 6
// baseline (208.112 us; speedup 1.0000x reference)
//
#include <hip/hip_runtime.h>

typedef unsigned short u16;
typedef unsigned int u32;
typedef __attribute__((ext_vector_type(8))) __bf16 bf16x8;
typedef __attribute__((ext_vector_type(4))) float f32x4;
typedef __attribute__((ext_vector_type(16))) float f32x16;

#define EMBED 1024
#define NB 2
#define LQ 2048
#define HEADS 16
#define DH 64
// log2(e) / sqrt(64) -- folded into Q at projection time
#define QSCALE 0.18033688011112042f

__device__ __forceinline__ u16 f2bf(float f) {
  u32 u = __float_as_uint(f);
  u32 r = (u + 0x7FFFu + ((u >> 16) & 1u)) >> 16;  // RNE
  return (u16)r;
}

__device__ __forceinline__ void glds16(const void* g, void* l) {
  __builtin_amdgcn_global_load_lds((const __attribute__((address_space(1))) void*)g,
                                   (__attribute__((address_space(3))) void*)l, 16, 0, 0);
}

__device__ __forceinline__ f32x4 mfma16(bf16x8 a, bf16x8 b, f32x4 c) {
  return __builtin_amdgcn_mfma_f32_16x16x32_bf16(a, b, c, 0, 0, 0);
}
__device__ __forceinline__ f32x16 mfma32(bf16x8 a, bf16x8 b, f32x16 c) {
  return __builtin_amdgcn_mfma_f32_32x32x16_bf16(a, b, c, 0, 0, 0);
}

// v_permlane32_swap_b32: a[l>=32] <-> b[l-32]. Register-only exchange.
__device__ __forceinline__ void pl32(u32& a, u32& b) {
  asm("v_permlane32_swap_b32 %0, %1" : "+v"(a), "+v"(b));
}

// pack two floats to bf16 pair (truncating): low = a, high = b
__device__ __forceinline__ u32 packbf(float a, float b) {
  return __builtin_amdgcn_perm(__float_as_uint(b), __float_as_uint(a), 0x07060302u);
}

// ---------------- cast fp32 -> bf16 for activations + weights ----------------
__global__ __launch_bounds__(256) void cast_kernel(
    const float* __restrict__ q, const float* __restrict__ kv,
    const float* __restrict__ wq, const float* __restrict__ wk,
    const float* __restrict__ wv, const float* __restrict__ wo,
    u16* __restrict__ qb, u16* __restrict__ kvb, u16* __restrict__ wqb,
    u16* __restrict__ wkb, u16* __restrict__ wvb, u16* __restrict__ wob) {
  int bid = blockIdx.x;
  const float* src;
  u16* dst;
  long base;
  if (bid < 2048) {
    src = q; dst = qb; base = (long)bid * 2048;
  } else if (bid < 4096) {
    src = kv; dst = kvb; base = (long)(bid - 2048) * 2048;
  } else {
    int wsel = (bid - 4096) >> 9;
    int wb = (bid - 4096) & 511;
    if (wsel == 0) { src = wq; dst = wqb; }
    else if (wsel == 1) { src = wk; dst = wkb; }
    else if (wsel == 2) { src = wv; dst = wvb; }
    else { src = wo; dst = wob; }
    base = (long)wb * 2048;
  }
  long e = base + (long)threadIdx.x * 8;
  float4 f0 = *(const float4*)(src + e);
  float4 f1 = *(const float4*)(src + e + 4);
  uint4 o;
  o.x = (u32)f2bf(f0.x) | ((u32)f2bf(f0.y) << 16);
  o.y = (u32)f2bf(f0.z) | ((u32)f2bf(f0.w) << 16);
  o.z = (u32)f2bf(f1.x) | ((u32)f2bf(f1.y) << 16);
  o.w = (u32)f2bf(f1.z) | ((u32)f2bf(f1.w) << 16);
  *(uint4*)(dst + e) = o;
}

// ------------- GEMM: C = A @ W^T (+bias, mode-specific epilogue), BK=64 ------
// mode 0: Q -> [bh][L][64], scaled by QSCALE; 1: K -> same layout unscaled;
// mode 2: V -> [bh][64][L] (transposed, b64-packed stores);
// mode 3: fp32 out = acc + bias + resid (pre-LN x).
// Fragments loaded per-ki (halves live frag registers -> more waves/CU).
template <int IT>
__device__ __forceinline__ void gemm_core(
    u16* As, u16* Bs, const u16* __restrict__ A, const u16* __restrict__ W,
    const float* __restrict__ bias, const float* __restrict__ resid,
    void* __restrict__ outp, int mode, int bx, int by) {
  const int K = EMBED;
  const int TM = IT * 32;
  const int tid = threadIdx.x;
  const int lane = tid & 63;
  const int wv = tid >> 6;
  const int wm = wv >> 1, wn = wv & 1;
  const int l16 = lane & 15, quad = lane >> 4;
  const long tile_m = (long)bx * TM;
  const long tile_n = (long)by * 128;

  f32x4 z4 = {0.f, 0.f, 0.f, 0.f};
  f32x4 acc[IT][4];
#pragma unroll
  for (int i = 0; i < IT; i++)
#pragma unroll
    for (int j = 0; j < 4; j++) acc[i][j] = z4;

  for (int k0 = 0; k0 < K; k0 += 64) {
    // stage A: TM rows x 8 chunks(16B), XOR swizzle cc ^ (row&7)
#pragma unroll
    for (int it = 0; it < TM / 32; it++) {
      int lin = it * 256 + tid;
      int row = lin >> 3, cc = lin & 7;
      glds16(A + (tile_m + row) * K + k0 + ((cc ^ (row & 7)) << 3), As + lin * 8);
    }
#pragma unroll
    for (int it = 0; it < 4; it++) {
      int lin = it * 256 + tid;
      int row = lin >> 3, cc = lin & 7;
      glds16(W + (tile_n + row) * K + k0 + ((cc ^ (row & 7)) << 3), Bs + lin * 8);
    }
    __syncthreads();
#pragma unroll
    for (int ki = 0; ki < 2; ki++) {
      bf16x8 af[IT], bfr[4];
#pragma unroll
      for (int i = 0; i < IT; i++) {
        int row = wm * (IT * 16) + i * 16 + l16;
        af[i] = *(const bf16x8*)(As + row * 64 + (((ki * 4 + quad) ^ (row & 7)) << 3));
      }
#pragma unroll
      for (int j = 0; j < 4; j++) {
        int row = wn * 64 + j * 16 + l16;
        bfr[j] = *(const bf16x8*)(Bs + row * 64 + (((ki * 4 + quad) ^ (row & 7)) << 3));
      }
#pragma unroll
      for (int i = 0; i < IT; i++)
#pragma unroll
        for (int j = 0; j < 4; j++) acc[i][j] = mfma16(af[i], bfr[j], acc[i][j]);
    }
    __syncthreads();
  }

  // epilogue: C/D layout col=lane&15, row=quad*4+r
#pragma unroll
  for (int j = 0; j < 4; j++) {
    int gn = (int)tile_n + wn * 64 + j * 16 + l16;
    float bv = bias[gn];
#pragma unroll
    for (int i = 0; i < IT; i++) {
      long gm0 = tile_m + wm * (IT * 16) + i * 16 + quad * 4;
      if (mode == 3) {
#pragma unroll
        for (int r = 0; r < 4; r++) {
          long idx = (gm0 + r) * EMBED + gn;
          ((float*)outp)[idx] = acc[i][j][r] + bv + resid[idx];
        }
      } else if (mode == 2) {
        // V^T: lane's 4 values are consecutive l at fixed dh -> one b64 store
        int b = (int)(gm0 >> 11), l = (int)(gm0 & 2047);
        int hh = gn >> 6, dh = gn & 63;
        uint2 pk;
        pk.x = (u32)f2bf(acc[i][j][0] + bv) | ((u32)f2bf(acc[i][j][1] + bv) << 16);
        pk.y = (u32)f2bf(acc[i][j][2] + bv) | ((u32)f2bf(acc[i][j][3] + bv) << 16);
        *(uint2*)((u16*)outp + (long)((b * HEADS + hh) * DH + dh) * LQ + l) = pk;
      } else {
#pragma unroll
        for (int r = 0; r < 4; r++) {
          long gm = gm0 + r;
          float v = acc[i][j][r] + bv;
          if (mode == 0) v *= QSCALE;
          int b = (int)(gm >> 11), l = (int)(gm & 2047);
          int hh = gn >> 6, dh = gn & 63;
          ((u16*)outp)[(long)((b * HEADS + hh) * LQ + l) * DH + dh] = f2bf(v);
        }
      }
    }
  }
}

// IT=2 (64-row tiles): 1536 blocks -> ~16 waves/CU for TLP.
__global__ __launch_bounds__(256, 4) void qkv_kernel(
    const u16* __restrict__ qb, const u16* __restrict__ kvb,
    const u16* __restrict__ wqb, const u16* __restrict__ wkb, const u16* __restrict__ wvb,
    const float* __restrict__ bq, const float* __restrict__ bk, const float* __restrict__ bv,
    u16* __restrict__ Qh, u16* __restrict__ Kh, u16* __restrict__ Vt) {
  __shared__ u16 As[64 * 64];    // 8 KB
  __shared__ u16 Bs[128 * 64];   // 16 KB
  if (blockIdx.z == 0)      gemm_core<2>(As, Bs, qb,  wqb, bq, nullptr, Qh, 0, blockIdx.x, blockIdx.y);
  else if (blockIdx.z == 1) gemm_core<2>(As, Bs, kvb, wkb, bk, nullptr, Kh, 1, blockIdx.x, blockIdx.y);
  else                      gemm_core<2>(As, Bs, kvb, wvb, bv, nullptr, Vt, 2, blockIdx.x, blockIdx.y);
}

__global__ __launch_bounds__(256, 4) void oproj_kernel(
    const u16* __restrict__ ctx, const u16* __restrict__ wob,
    const float* __restrict__ bo, const float* __restrict__ resid, float* __restrict__ out) {
  __shared__ u16 As[64 * 64];    // 8 KB
  __shared__ u16 Bs[128 * 64];   // 16 KB
  gemm_core<2>(As, Bs, ctx, wob, bo, resid, out, 3, blockIdx.x, blockIdx.y);
}

// ---- flash attention: ring-4 + counted vmcnt + XCD swizzle + SM/S interleave
// R5 verified schedule (49.4us) with two independent latency fixes:
//  (1) T1 XCD swizzle: flat grid 512 (%8==0 -> bijective); XCD x owns bh in
//      [4x,4x+4) -> per-XCD K/V+Q working set ~3 MB < 4 MB L2 (was: every XCD
//      touched all 32 bh = 16 MB -> chronic L2 thrash, FETCH 70 MB vs 24
//      ideal).
//  (2) intra-iteration interleave, ZERO new accumulator state (R4's sta/stb
//      spill lesson): split SM and S into mt-halves ordered SM0,S0,SM1,S1 --
//      the register WAR (SM reads st[mt] before S overwrites) is preserved
//      per-half, so S's matrix ops run while SM1's exp/pack VALU issues.
//      K-frags pre-loaded to regs at iter top (LDS latency hides under SM0);
//      V-frags loaded before PL so the 8 permlane swaps cover their latency;
//      PV is then 8 back-to-back reg-only MFMAs. +64 VGPR (~156 total), safe
//      at 2 waves/SIMD (256 cap).
__global__ __launch_bounds__(256, 2) void attn_kernel(
    const u16* __restrict__ Qh, const u16* __restrict__ Kh,
    const u16* __restrict__ Vt, u16* __restrict__ ctx) {
  __shared__ u16 KVs[4][2][64 * 64];  // 64 KB: ring[4] x [K/V] x 64x64
  const int tid = threadIdx.x;
  const int lane = tid & 63;
  const int wv = tid >> 6;             // wave owns qrows wv*32 .. wv*32+31
  const int l32 = lane & 31, h = lane >> 5;
  // XCD swizzle (XCD = blockIdx%8): XCD x -> swz in [64x, 64x+64) -> bh chunk
  const int bid = (int)blockIdx.x;
  const int swz = (bid & 7) * 64 + (bid >> 3);
  const int bh = swz >> 4, qt = swz & 15;
  const long qoff = (long)bh * (LQ * DH) + (long)qt * (128 * DH);
  const long koff = (long)bh * (LQ * DH);
  const long voff = (long)bh * (DH * LQ);
  const int qbase = wv * 32;

// stage K/V tile t into ring slot N (N literal -> const LDS dest); 4 vm ops
#define STAGE_KV(t, N)                                                          \
  do {                                                                          \
    _Pragma("unroll") for (int it = 0; it < 2; it++) {                          \
      int lin = it * 256 + tid;                                                 \
      int row = lin >> 3, cc = lin & 7;                                         \
      glds16(Kh + koff + (long)((t) * 64 + row) * 64 + ((cc ^ (row & 7)) << 3), \
             &KVs[N][0][0] + lin * 8);                                          \
      glds16(Vt + voff + (long)row * LQ + (t) * 64 + ((cc ^ (row & 7)) << 3),   \
             &KVs[N][1][0] + lin * 8);                                          \
    }                                                                           \
  } while (0)

// counted-drain barrier: allow the W newest vmem ops to stay in flight.
#define SYNC(W)                                                                 \
  do {                                                                          \
    asm volatile("s_waitcnt vmcnt(" #W ")" ::: "memory");                       \
    __builtin_amdgcn_s_barrier();                                               \
    asm volatile("" ::: "memory");                                              \
  } while (0)

  // Q B-frags direct from global: qrow = qbase+l32, d-chunk = ks*16+8h+(0..7)
  bf16x8 bq[4];
  {
    const u16* qp = Qh + qoff + (qbase + l32) * 64 + h * 8;
#pragma unroll
    for (int ks = 0; ks < 4; ks++) bq[ks] = *(const bf16x8*)(qp + ks * 16);
  }

  STAGE_KV(0, 0);
  STAGE_KV(1, 1);
  STAGE_KV(2, 2);
  SYNC(4);  // bq + tiles 0,1 landed; tile 2's 4 ops may fly

  f32x16 z16 = {0.f, 0.f, 0.f, 0.f, 0.f, 0.f, 0.f, 0.f,
                0.f, 0.f, 0.f, 0.f, 0.f, 0.f, 0.f, 0.f};
  f32x16 ot[2];
  ot[0] = z16;
  ot[1] = z16;
  f32x16 st[2];
  uint2 pk[2][4];
  bf16x8 ak[4][2], av[4][2], bpv[4];
  float2 ls2 = {0.f, 0.f};

// K-frags of ring slot C -> registers (8 ds_read_b128)
#define LOAD_K(C)                                                                \
  do {                                                                           \
    _Pragma("unroll") for (int ks = 0; ks < 4; ks++) {                           \
      _Pragma("unroll") for (int mt = 0; mt < 2; mt++) {                         \
        int row = mt * 32 + l32;                                                 \
        ak[ks][mt] = *(const bf16x8*)(&KVs[C][0][0] + row * 64 +                 \
                                      (((ks * 2 + h) ^ (row & 7)) << 3));        \
      }                                                                          \
    }                                                                            \
  } while (0)

// V^T-frags of ring slot P -> registers (8 ds_read_b128)
#define LOAD_V(P)                                                                \
  do {                                                                           \
    _Pragma("unroll") for (int s = 0; s < 4; s++) {                              \
      _Pragma("unroll") for (int mt2 = 0; mt2 < 2; mt2++) {                      \
        int row = mt2 * 32 + l32;                                                \
        av[s][mt2] = *(const bf16x8*)(&KVs[P][1][0] + row * 64 +                 \
                                      ((((s << 1) + h) ^ (row & 7)) << 3));      \
      }                                                                          \
    }                                                                            \
  } while (0)

// S^T half: st[MT] = K(mt=MT) . Q^T over 4 ksteps (reg-only MFMAs);
// ks==0 uses the hoisted zero vector as C -> no accumulator zero-init movs.
#define DO_S_H(MT)                                                               \
  do {                                                                           \
    __builtin_amdgcn_s_setprio(1);                                               \
    _Pragma("unroll") for (int ks = 0; ks < 4; ks++)                             \
        st[MT] = mfma32(ak[ks][MT], bq[ks], (ks == 0) ? z16 : st[MT]);           \
    __builtin_amdgcn_s_setprio(0);                                               \
  } while (0)

// softmax half MT: p = 2^st[MT] via raw v_exp_f32 -> pk[MT] (reads st[MT]
// BEFORE DO_S_H(MT) overwrites it -- WAR in program order, no extra regs)
#define DO_SM_H(MT)                                                              \
  do {                                                                           \
    _Pragma("unroll") for (int g = 0; g < 4; g++) {                              \
      float p0 = __builtin_amdgcn_exp2f(st[MT][g * 4 + 0]);                      \
      float p1 = __builtin_amdgcn_exp2f(st[MT][g * 4 + 1]);                      \
      float p2 = __builtin_amdgcn_exp2f(st[MT][g * 4 + 2]);                      \
      float p3 = __builtin_amdgcn_exp2f(st[MT][g * 4 + 3]);                      \
      ls2.x += p0 + p2;                                                          \
      ls2.y += p1 + p3;                                                          \
      pk[MT][g].x = packbf(p0, p1);                                              \
      pk[MT][g].y = packbf(p2, p3);                                              \
    }                                                                            \
  } while (0)

// assemble all 4 PV B-frags (keys 16s+8h+{0..7}) from pk via 8 permlane swaps
#define DO_PL()                                                                  \
  do {                                                                           \
    _Pragma("unroll") for (int s = 0; s < 4; s++) {                              \
      uint2 wa = pk[s >> 1][(s & 1) * 2];                                        \
      uint2 wb = pk[s >> 1][(s & 1) * 2 + 1];                                    \
      u32 a0 = wa.x, b0 = wb.x, a1 = wa.y, b1 = wb.y;                            \
      pl32(a0, b0);                                                              \
      pl32(a1, b1);                                                              \
      union { u32 u[4]; bf16x8 v; } bp;                                          \
      bp.u[0] = a0;                                                              \
      bp.u[1] = a1;                                                              \
      bp.u[2] = b0;                                                              \
      bp.u[3] = b1;                                                              \
      bpv[s] = bp.v;                                                             \
    }                                                                            \
  } while (0)

// O^T += V^T . P : 8 back-to-back reg-only MFMAs
#define DO_PV()                                                                  \
  do {                                                                           \
    __builtin_amdgcn_s_setprio(1);                                               \
    _Pragma("unroll") for (int s = 0; s < 4; s++) {                              \
      _Pragma("unroll") for (int mt2 = 0; mt2 < 2; mt2++)                        \
          ot[mt2] = mfma32(av[s][mt2], bpv[s], ot[mt2]);                         \
    }                                                                            \
    __builtin_amdgcn_s_setprio(0);                                               \
  } while (0)

// iteration (tile kt): stage kt+2 -> N; K-frags of kt -> regs (latency under
// SM0); SM0(kt-1) | S0(kt) | SM1(kt-1) | S1(kt) interleave; V-frags of kt-1
// (latency under PL swaps); PV(kt-1); counted barrier. Slot of tile t = t&3.
#define AITER(kt, P, C, N, W)                                                    \
  do {                                                                           \
    if ((kt) + 2 < 32) STAGE_KV((kt) + 2, N);                                    \
    LOAD_K(C);                                                                   \
    DO_SM_H(0);                                                                  \
    DO_S_H(0);                                                                   \
    DO_SM_H(1);                                                                  \
    DO_S_H(1);                                                                   \
    LOAD_V(P);                                                                   \
    DO_PL();                                                                     \
    DO_PV();                                                                     \
    SYNC(W);                                                                     \
  } while (0)

  // prologue: scores of tile 0 (softmax'd in iter 1)
  LOAD_K(0);
  DO_S_H(0);
  DO_S_H(1);

  AITER(1, 0, 1, 3, 4);
  for (int k0 = 2; k0 < 30; k0 += 4) {  // k0 = 2,6,...,26 -> kt = 2..29
    AITER(k0 + 0, 1, 2, 0, 4);
    AITER(k0 + 1, 2, 3, 1, 4);
    AITER(k0 + 2, 3, 0, 2, 4);
    AITER(k0 + 3, 0, 1, 3, 4);
  }
  AITER(30, 1, 2, 0, 0);  // no stage; full drain so tile 31 is landed
  AITER(31, 2, 3, 1, 0);  // no stage
  // tail: softmax + PV of tile 31 (slot 3)
  DO_SM_H(0);
  DO_SM_H(1);
  LOAD_V(3);
  DO_PL();
  DO_PV();

#undef STAGE_KV
#undef SYNC
#undef LOAD_K
#undef LOAD_V
#undef DO_S_H
#undef DO_SM_H
#undef DO_PL
#undef DO_PV
#undef AITER

  // lsum: fold float2 + combine the two lane-halves holding the same qrow
  float lsum = ls2.x + ls2.y;
  lsum += __shfl_xor(lsum, 32);
  float inv = 1.0f / lsum;

  // epilogue: lane holds qrow = qt*128 + qbase + l32, d = mt*32 + g*8 + 4h + r
  const int b = bh >> 4, head = bh & 15;
  int qrow = qt * 128 + qbase + l32;
  long base = (long)(b * LQ + qrow) * EMBED + head * DH;
#pragma unroll
  for (int mt = 0; mt < 2; mt++) {
#pragma unroll
    for (int g = 0; g < 4; g++) {
      uint2 pkk;
      pkk.x = (u32)f2bf(ot[mt][g * 4 + 0] * inv) | ((u32)f2bf(ot[mt][g * 4 + 1] * inv) << 16);
      pkk.y = (u32)f2bf(ot[mt][g * 4 + 2] * inv) | ((u32)f2bf(ot[mt][g * 4 + 3] * inv) << 16);
      *(uint2*)(ctx + base + mt * 32 + g * 8 + 4 * h) = pkk;
    }
  }
}

// ---------------- LayerNorm in place on d_out ----------------
__global__ __launch_bounds__(256) void ln_kernel(
    float* __restrict__ x, const float* __restrict__ gamma, const float* __restrict__ beta) {
  __shared__ float red[8];
  const int tid = threadIdx.x;
  const long row = blockIdx.x;
  float4 v = *(const float4*)(x + row * EMBED + tid * 4);
  float s = v.x + v.y + v.z + v.w;
  float sq = v.x * v.x + v.y * v.y + v.z * v.z + v.w * v.w;
#pragma unroll
  for (int off = 1; off < 64; off <<= 1) {
    s += __shfl_xor(s, off);
    sq += __shfl_xor(sq, off);
  }
  if ((tid & 63) == 0) {
    red[(tid >> 6) * 2] = s;
    red[(tid >> 6) * 2 + 1] = sq;
  }
  __syncthreads();
  s = red[0] + red[2] + red[4] + red[6];
  sq = red[1] + red[3] + red[5] + red[7];
  float mu = s * (1.f / EMBED);
  float var = sq * (1.f / EMBED) - mu * mu;
  float rstd = rsqrtf(var + 1e-5f);
  float4 g = *(const float4*)(gamma + tid * 4);
  float4 bt = *(const float4*)(beta + tid * 4);
  float4 ov;
  ov.x = (v.x - mu) * rstd * g.x + bt.x;
  ov.y = (v.y - mu) * rstd * g.y + bt.y;
  ov.z = (v.z - mu) * rstd * g.z + bt.z;
  ov.w = (v.w - mu) * rstd * g.w + bt.w;
  *(float4*)(x + row * EMBED + tid * 4) = ov;
}

extern "C" void kernel_launch(void* const* d_in, const int* in_sizes, int n_in,
                              void* d_out, int out_size, void* d_ws, size_t ws_size,
                              hipStream_t stream) {
  const float* q     = (const float*)d_in[0];
  const float* kv    = (const float*)d_in[1];
  // d_in[2] = prompt_size (0, unused)
  const float* Wq    = (const float*)d_in[3];
  const float* bq    = (const float*)d_in[4];
  const float* Wk    = (const float*)d_in[5];
  const float* bk    = (const float*)d_in[6];
  const float* Wv    = (const float*)d_in[7];
  const float* bv    = (const float*)d_in[8];
  const float* Wo    = (const float*)d_in[9];
  const float* bo    = (const float*)d_in[10];
  const float* gamma = (const float*)d_in[11];
  const float* beta  = (const float*)d_in[12];

  char* ws = (char*)d_ws;
  u16* qb  = (u16*)(ws + (0l  << 20));  // 8 MB
  u16* kvb = (u16*)(ws + (8l  << 20));  // 8 MB
  u16* wqb = (u16*)(ws + (16l << 20));  // 2 MB
  u16* wkb = (u16*)(ws + (18l << 20));
  u16* wvb = (u16*)(ws + (20l << 20));
  u16* wob = (u16*)(ws + (22l << 20));
  u16* Qh  = (u16*)(ws + (24l << 20));  // 8 MB [bh][L][64] (pre-scaled by QSCALE)
  u16* Kh  = (u16*)(ws + (32l << 20));  // 8 MB [bh][L][64]
  u16* Vt  = (u16*)(ws + (40l << 20));  // 8 MB [bh][64][L]
  u16* ctx = (u16*)(ws + (48l << 20));  // 8 MB [B][L][E]   (total 56 MB)
  float* out = (float*)d_out;

  cast_kernel<<<6144, 256, 0, stream>>>(q, kv, Wq, Wk, Wv, Wo, qb, kvb, wqb, wkb, wvb, wob);
  qkv_kernel<<<dim3(64, 8, 3), 256, 0, stream>>>(qb, kvb, wqb, wkb, wvb, bq, bk, bv, Qh, Kh, Vt);
  attn_kernel<<<512, 256, 0, stream>>>(Qh, Kh, Vt, ctx);
  oproj_kernel<<<dim3(64, 8), 256, 0, stream>>>(ctx, wob, bo, q, out);
  ln_kernel<<<4096, 256, 0, stream>>>(out, gamma, beta);
}

// Round 7
// 206.234 us; speedup vs baseline: 1.0091x; 1.0091x over previous
//
#include <hip/hip_runtime.h>

typedef unsigned short u16;
typedef unsigned int u32;
typedef __attribute__((ext_vector_type(8))) __bf16 bf16x8;
typedef __attribute__((ext_vector_type(4))) float f32x4;
typedef __attribute__((ext_vector_type(16))) float f32x16;

#define EMBED 1024
#define NB 2
#define LQ 2048
#define HEADS 16
#define DH 64
// log2(e) / sqrt(64) -- folded into Q at projection time
#define QSCALE 0.18033688011112042f

__device__ __forceinline__ u16 f2bf(float f) {
  u32 u = __float_as_uint(f);
  u32 r = (u + 0x7FFFu + ((u >> 16) & 1u)) >> 16;  // RNE
  return (u16)r;
}

__device__ __forceinline__ void glds16(const void* g, void* l) {
  __builtin_amdgcn_global_load_lds((const __attribute__((address_space(1))) void*)g,
                                   (__attribute__((address_space(3))) void*)l, 16, 0, 0);
}

__device__ __forceinline__ f32x4 mfma16(bf16x8 a, bf16x8 b, f32x4 c) {
  return __builtin_amdgcn_mfma_f32_16x16x32_bf16(a, b, c, 0, 0, 0);
}
__device__ __forceinline__ f32x16 mfma32(bf16x8 a, bf16x8 b, f32x16 c) {
  return __builtin_amdgcn_mfma_f32_32x32x16_bf16(a, b, c, 0, 0, 0);
}

// v_permlane32_swap_b32: a[l>=32] <-> b[l-32]. Register-only exchange.
__device__ __forceinline__ void pl32(u32& a, u32& b) {
  asm("v_permlane32_swap_b32 %0, %1" : "+v"(a), "+v"(b));
}

// pack two floats to bf16 pair (truncating): low = a, high = b
__device__ __forceinline__ u32 packbf(float a, float b) {
  return __builtin_amdgcn_perm(__float_as_uint(b), __float_as_uint(a), 0x07060302u);
}

// ---------------- cast fp32 -> bf16 for activations + weights ----------------
__global__ __launch_bounds__(256) void cast_kernel(
    const float* __restrict__ q, const float* __restrict__ kv,
    const float* __restrict__ wq, const float* __restrict__ wk,
    const float* __restrict__ wv, const float* __restrict__ wo,
    u16* __restrict__ qb, u16* __restrict__ kvb, u16* __restrict__ wqb,
    u16* __restrict__ wkb, u16* __restrict__ wvb, u16* __restrict__ wob) {
  int bid = blockIdx.x;
  const float* src;
  u16* dst;
  long base;
  if (bid < 2048) {
    src = q; dst = qb; base = (long)bid * 2048;
  } else if (bid < 4096) {
    src = kv; dst = kvb; base = (long)(bid - 2048) * 2048;
  } else {
    int wsel = (bid - 4096) >> 9;
    int wb = (bid - 4096) & 511;
    if (wsel == 0) { src = wq; dst = wqb; }
    else if (wsel == 1) { src = wk; dst = wkb; }
    else if (wsel == 2) { src = wv; dst = wvb; }
    else { src = wo; dst = wob; }
    base = (long)wb * 2048;
  }
  long e = base + (long)threadIdx.x * 8;
  float4 f0 = *(const float4*)(src + e);
  float4 f1 = *(const float4*)(src + e + 4);
  uint4 o;
  o.x = (u32)f2bf(f0.x) | ((u32)f2bf(f0.y) << 16);
  o.y = (u32)f2bf(f0.z) | ((u32)f2bf(f0.w) << 16);
  o.z = (u32)f2bf(f1.x) | ((u32)f2bf(f1.y) << 16);
  o.w = (u32)f2bf(f1.z) | ((u32)f2bf(f1.w) << 16);
  *(uint4*)(dst + e) = o;
}

// ------------- GEMM: C = A @ W^T (+bias, mode-specific epilogue), BK=64 ------
// mode 0: Q -> [bh][L][64], scaled by QSCALE; 1: K -> same layout unscaled;
// mode 2: V -> [bh][64][L] (transposed, b64-packed stores);
// mode 3: fp32 out = acc + bias + resid (pre-LN x).
// Fragments loaded per-ki (halves live frag registers -> more waves/CU).
template <int IT>
__device__ __forceinline__ void gemm_core(
    u16* As, u16* Bs, const u16* __restrict__ A, const u16* __restrict__ W,
    const float* __restrict__ bias, const float* __restrict__ resid,
    void* __restrict__ outp, int mode, int bx, int by) {
  const int K = EMBED;
  const int TM = IT * 32;
  const int tid = threadIdx.x;
  const int lane = tid & 63;
  const int wv = tid >> 6;
  const int wm = wv >> 1, wn = wv & 1;
  const int l16 = lane & 15, quad = lane >> 4;
  const long tile_m = (long)bx * TM;
  const long tile_n = (long)by * 128;

  f32x4 z4 = {0.f, 0.f, 0.f, 0.f};
  f32x4 acc[IT][4];
#pragma unroll
  for (int i = 0; i < IT; i++)
#pragma unroll
    for (int j = 0; j < 4; j++) acc[i][j] = z4;

  for (int k0 = 0; k0 < K; k0 += 64) {
    // stage A: TM rows x 8 chunks(16B), XOR swizzle cc ^ (row&7)
#pragma unroll
    for (int it = 0; it < TM / 32; it++) {
      int lin = it * 256 + tid;
      int row = lin >> 3, cc = lin & 7;
      glds16(A + (tile_m + row) * K + k0 + ((cc ^ (row & 7)) << 3), As + lin * 8);
    }
#pragma unroll
    for (int it = 0; it < 4; it++) {
      int lin = it * 256 + tid;
      int row = lin >> 3, cc = lin & 7;
      glds16(W + (tile_n + row) * K + k0 + ((cc ^ (row & 7)) << 3), Bs + lin * 8);
    }
    __syncthreads();
#pragma unroll
    for (int ki = 0; ki < 2; ki++) {
      bf16x8 af[IT], bfr[4];
#pragma unroll
      for (int i = 0; i < IT; i++) {
        int row = wm * (IT * 16) + i * 16 + l16;
        af[i] = *(const bf16x8*)(As + row * 64 + (((ki * 4 + quad) ^ (row & 7)) << 3));
      }
#pragma unroll
      for (int j = 0; j < 4; j++) {
        int row = wn * 64 + j * 16 + l16;
        bfr[j] = *(const bf16x8*)(Bs + row * 64 + (((ki * 4 + quad) ^ (row & 7)) << 3));
      }
#pragma unroll
      for (int i = 0; i < IT; i++)
#pragma unroll
        for (int j = 0; j < 4; j++) acc[i][j] = mfma16(af[i], bfr[j], acc[i][j]);
    }
    __syncthreads();
  }

  // epilogue: C/D layout col=lane&15, row=quad*4+r
#pragma unroll
  for (int j = 0; j < 4; j++) {
    int gn = (int)tile_n + wn * 64 + j * 16 + l16;
    float bv = bias[gn];
#pragma unroll
    for (int i = 0; i < IT; i++) {
      long gm0 = tile_m + wm * (IT * 16) + i * 16 + quad * 4;
      if (mode == 3) {
#pragma unroll
        for (int r = 0; r < 4; r++) {
          long idx = (gm0 + r) * EMBED + gn;
          ((float*)outp)[idx] = acc[i][j][r] + bv + resid[idx];
        }
      } else if (mode == 2) {
        // V^T: lane's 4 values are consecutive l at fixed dh -> one b64 store
        int b = (int)(gm0 >> 11), l = (int)(gm0 & 2047);
        int hh = gn >> 6, dh = gn & 63;
        uint2 pk;
        pk.x = (u32)f2bf(acc[i][j][0] + bv) | ((u32)f2bf(acc[i][j][1] + bv) << 16);
        pk.y = (u32)f2bf(acc[i][j][2] + bv) | ((u32)f2bf(acc[i][j][3] + bv) << 16);
        *(uint2*)((u16*)outp + (long)((b * HEADS + hh) * DH + dh) * LQ + l) = pk;
      } else {
#pragma unroll
        for (int r = 0; r < 4; r++) {
          long gm = gm0 + r;
          float v = acc[i][j][r] + bv;
          if (mode == 0) v *= QSCALE;
          int b = (int)(gm >> 11), l = (int)(gm & 2047);
          int hh = gn >> 6, dh = gn & 63;
          ((u16*)outp)[(long)((b * HEADS + hh) * LQ + l) * DH + dh] = f2bf(v);
        }
      }
    }
  }
}

// IT=2 (64-row tiles): 1536 blocks -> ~16 waves/CU for TLP.
__global__ __launch_bounds__(256, 4) void qkv_kernel(
    const u16* __restrict__ qb, const u16* __restrict__ kvb,
    const u16* __restrict__ wqb, const u16* __restrict__ wkb, const u16* __restrict__ wvb,
    const float* __restrict__ bq, const float* __restrict__ bk, const float* __restrict__ bv,
    u16* __restrict__ Qh, u16* __restrict__ Kh, u16* __restrict__ Vt) {
  __shared__ u16 As[64 * 64];    // 8 KB
  __shared__ u16 Bs[128 * 64];   // 16 KB
  if (blockIdx.z == 0)      gemm_core<2>(As, Bs, qb,  wqb, bq, nullptr, Qh, 0, blockIdx.x, blockIdx.y);
  else if (blockIdx.z == 1) gemm_core<2>(As, Bs, kvb, wkb, bk, nullptr, Kh, 1, blockIdx.x, blockIdx.y);
  else                      gemm_core<2>(As, Bs, kvb, wvb, bv, nullptr, Vt, 2, blockIdx.x, blockIdx.y);
}

__global__ __launch_bounds__(256, 4) void oproj_kernel(
    const u16* __restrict__ ctx, const u16* __restrict__ wob,
    const float* __restrict__ bo, const float* __restrict__ resid, float* __restrict__ out) {
  __shared__ u16 As[64 * 64];    // 8 KB
  __shared__ u16 Bs[128 * 64];   // 16 KB
  gemm_core<2>(As, Bs, ctx, wob, bo, resid, out, 3, blockIdx.x, blockIdx.y);
}

// ---- flash attention: 8-wave blocks (4 qsub x 2 key-halves), ring-4+vmcnt ---
// R6 was issue-limited at 2 waves/SIMD (wall 1732 cyc/slot vs ~1140 busy
// floor; FETCH fix confirmed but dur barely moved). Grid is capacity-matched
// (512 blocks = 2/CU), so the only TLP lever is BIGGER BLOCKS: 512 threads =
// 8 waves = 4 qsub x 2 key-halves. Wave (qsub,kh) owns 32 qrows x keys
// [32kh,32kh+32) of each 64-key tile -> per-wave work halves (8 MFMA, 16 exp,
// 4 swaps, 8 ds_reads/iter), LDS/wave halves -> 2 blocks/CU = 4 waves/SIMD.
// Schedule preserved from R6: ring-4 (slot t&3), stage t+2, counted
// s_waitcnt vmcnt(2) (2 vm ops/wave/iter), XCD swizzle. LDS reads inline
// (no frag arrays) to stay under the 128-VGPR cap of launch_bounds(512,4)
// (R4 spill lesson: watch WRITE_SIZE). K-half partials merge ADDITIVELY
// (no max-tracking) via one LDS exchange reusing the ring after the loop.
__global__ __launch_bounds__(512, 4) void attn_kernel(
    const u16* __restrict__ Qh, const u16* __restrict__ Kh,
    const u16* __restrict__ Vt, u16* __restrict__ ctx) {
  __shared__ u16 KVs[4][2][64 * 64];  // 64 KB: ring[4] x [K/V] x 64x64
  const int tid = threadIdx.x;
  const int lane = tid & 63;
  const int wv = tid >> 6;            // 8 waves
  const int qsub = wv >> 1;           // 4 q-subtiles of 32 rows
  const int kh = wv & 1;              // key half within each 64-key tile
  const int l32 = lane & 31, h = lane >> 5;
  // XCD swizzle (XCD = blockIdx%8): XCD x -> swz in [64x, 64x+64) -> bh chunk
  const int bid = (int)blockIdx.x;
  const int swz = (bid & 7) * 64 + (bid >> 3);
  const int bh = swz >> 4, qt = swz & 15;
  const long qoff = (long)bh * (LQ * DH) + (long)qt * (128 * DH);
  const long koff = (long)bh * (LQ * DH);
  const long voff = (long)bh * (DH * LQ);
  const int qbase = qsub * 32;
  const int krow = kh * 32 + l32;     // wave's K-row (key) in the 64-key tile

// stage K/V tile t into ring slot N; 512 threads cover 8KB each in ONE pass
// -> 2 vm ops per wave per stage
#define STAGE_KV(t, N)                                                          \
  do {                                                                          \
    int row = tid >> 3, cc = tid & 7;                                           \
    glds16(Kh + koff + (long)((t) * 64 + row) * 64 + ((cc ^ (row & 7)) << 3),   \
           &KVs[N][0][0] + tid * 8);                                            \
    glds16(Vt + voff + (long)row * LQ + (t) * 64 + ((cc ^ (row & 7)) << 3),     \
           &KVs[N][1][0] + tid * 8);                                            \
  } while (0)

// counted-drain barrier: allow the W newest vmem ops to stay in flight.
#define SYNC(W)                                                                 \
  do {                                                                          \
    asm volatile("s_waitcnt vmcnt(" #W ")" ::: "memory");                       \
    __builtin_amdgcn_s_barrier();                                               \
    asm volatile("" ::: "memory");                                              \
  } while (0)

  // Q B-frags direct from global: qrow = qbase+l32, d-chunk = ks*16+8h+(0..7)
  bf16x8 bq[4];
  {
    const u16* qp = Qh + qoff + (qbase + l32) * 64 + h * 8;
#pragma unroll
    for (int ks = 0; ks < 4; ks++) bq[ks] = *(const bf16x8*)(qp + ks * 16);
  }

  STAGE_KV(0, 0);
  STAGE_KV(1, 1);
  STAGE_KV(2, 2);
  SYNC(2);  // bq + tiles 0,1 landed; tile 2's 2 ops may fly

  f32x16 z16 = {0.f, 0.f, 0.f, 0.f, 0.f, 0.f, 0.f, 0.f,
                0.f, 0.f, 0.f, 0.f, 0.f, 0.f, 0.f, 0.f};
  f32x16 ot[2];
  ot[0] = z16;
  ot[1] = z16;
  f32x16 st;            // S^T scores for this wave's 32 keys x 32 qrows
  uint2 pk[4];          // packed exp'd scores (this wave's key half)
  float2 ls2 = {0.f, 0.f};

// S^T = K(half kh) . Q^T from ring slot C into st; inline ds_reads.
// ks==0 uses the hoisted zero vector as C -> no accumulator zero-init movs.
#define DO_S(C)                                                                  \
  do {                                                                           \
    __builtin_amdgcn_s_setprio(1);                                               \
    _Pragma("unroll") for (int ks = 0; ks < 4; ks++) {                           \
      bf16x8 ak = *(const bf16x8*)(&KVs[C][0][0] + krow * 64 +                   \
                                   (((ks * 2 + h) ^ (krow & 7)) << 3));          \
      st = mfma32(ak, bq[ks], (ks == 0) ? z16 : st);                             \
    }                                                                            \
    __builtin_amdgcn_s_setprio(0);                                               \
  } while (0)

// p = 2^st via raw v_exp_f32; lane's scores: qrow = qbase+l32,
// key = 32kh + 8g + 4h + r
#define DO_SM()                                                                  \
  do {                                                                           \
    _Pragma("unroll") for (int g = 0; g < 4; g++) {                              \
      float p0 = __builtin_amdgcn_exp2f(st[g * 4 + 0]);                          \
      float p1 = __builtin_amdgcn_exp2f(st[g * 4 + 1]);                          \
      float p2 = __builtin_amdgcn_exp2f(st[g * 4 + 2]);                          \
      float p3 = __builtin_amdgcn_exp2f(st[g * 4 + 3]);                          \
      ls2.x += p0 + p2;                                                          \
      ls2.y += p1 + p3;                                                          \
      pk[g].x = packbf(p0, p1);                                                  \
      pk[g].y = packbf(p2, p3);                                                  \
    }                                                                            \
  } while (0)

// O^T(partial over this wave's keys) += V^T . P from ring slot P.
// kstep s' in {0,1} covers keys 32kh+16s'..+15; B-frag words (keys
// 32kh+16s'+8h+{0..7}) from own pk + cross-half partner via permlane32_swap.
// V^T chunk c = (2*(2kh+s')+h) -> keys c*8..c*8+7.
#define DO_PV(P)                                                                 \
  do {                                                                           \
    _Pragma("unroll") for (int s = 0; s < 2; s++) {                              \
      uint2 wa = pk[s * 2];                                                      \
      uint2 wb = pk[s * 2 + 1];                                                  \
      u32 a0 = wa.x, b0 = wb.x, a1 = wa.y, b1 = wb.y;                            \
      pl32(a0, b0);                                                              \
      pl32(a1, b1);                                                              \
      union { u32 u[4]; bf16x8 v; } bp;                                          \
      bp.u[0] = a0;                                                              \
      bp.u[1] = a1;                                                              \
      bp.u[2] = b0;                                                              \
      bp.u[3] = b1;                                                              \
      __builtin_amdgcn_s_setprio(1);                                             \
      _Pragma("unroll") for (int mt2 = 0; mt2 < 2; mt2++) {                      \
        int row = mt2 * 32 + l32;                                                \
        int c = ((2 * kh + s) << 1) + h;                                         \
        bf16x8 av = *(const bf16x8*)(&KVs[P][1][0] + row * 64 +                  \
                                     ((c ^ (row & 7)) << 3));                    \
        ot[mt2] = mfma32(av, bp.v, ot[mt2]);                                     \
      }                                                                          \
      __builtin_amdgcn_s_setprio(0);                                             \
    }                                                                            \
  } while (0)

// iteration (tile kt): stage kt+2 -> N; softmax of kt-1 (st, WAR before S
// overwrites); S of kt from C; PV of kt-1 from P; counted barrier.
#define AITER(kt, P, C, N, W)                                                    \
  do {                                                                           \
    if ((kt) + 2 < 32) STAGE_KV((kt) + 2, N);                                    \
    DO_SM();                                                                     \
    DO_S(C);                                                                     \
    DO_PV(P);                                                                    \
    SYNC(W);                                                                     \
  } while (0)

  DO_S(0);  // prologue: scores of tile 0 (softmax'd in iter 1)

  AITER(1, 0, 1, 3, 2);
  for (int k0 = 2; k0 < 30; k0 += 4) {  // k0 = 2,6,...,26 -> kt = 2..29
    AITER(k0 + 0, 1, 2, 0, 2);
    AITER(k0 + 1, 2, 3, 1, 2);
    AITER(k0 + 2, 3, 0, 2, 2);
    AITER(k0 + 3, 0, 1, 3, 2);
  }
  AITER(30, 1, 2, 0, 0);  // no stage; full drain so tile 31 is landed
  AITER(31, 2, 3, 1, 0);  // no stage
  // tail: softmax + PV of tile 31 (slot 3)
  DO_SM();
  DO_PV(3);

#undef STAGE_KV
#undef SYNC
#undef DO_S
#undef DO_SM
#undef DO_PV
#undef AITER

  // partial lsum: fold float2 + combine the two lane-halves (same qrow)
  float lsum = ls2.x + ls2.y;
  lsum += __shfl_xor(lsum, 32);

  // ---- merge the two key-halves (additive; ring LDS reused) ----
  // mrg[qsub][lane][36pad]: 36 floats stride = 144B (16B-aligned, 4-way max)
  float* mrgf = (float*)(&KVs[0][0][0]);
  float* mlsf = mrgf + 4 * 64 * 36;  // 36864B + 1KB <= 64KB
  __syncthreads();  // all ring reads done before overwrite
  if (kh == 1) {
    int mbase = (qsub * 64 + lane) * 36;
#pragma unroll
    for (int mt2 = 0; mt2 < 2; mt2++)
#pragma unroll
      for (int e = 0; e < 16; e++) mrgf[mbase + mt2 * 16 + e] = ot[mt2][e];
    mlsf[qsub * 64 + lane] = lsum;
  }
  __syncthreads();
  if (kh == 0) {
    int mbase = (qsub * 64 + lane) * 36;
    lsum += mlsf[qsub * 64 + lane];
    float inv = 1.0f / lsum;
    // epilogue: lane holds qrow = qt*128 + qbase + l32, d = mt2*32 + g*8+4h+r
    const int b = bh >> 4, head = bh & 15;
    int qrow = qt * 128 + qbase + l32;
    long base = (long)(b * LQ + qrow) * EMBED + head * DH;
#pragma unroll
    for (int mt2 = 0; mt2 < 2; mt2++) {
#pragma unroll
      for (int g = 0; g < 4; g++) {
        float o0 = (ot[mt2][g * 4 + 0] + mrgf[mbase + mt2 * 16 + g * 4 + 0]) * inv;
        float o1 = (ot[mt2][g * 4 + 1] + mrgf[mbase + mt2 * 16 + g * 4 + 1]) * inv;
        float o2 = (ot[mt2][g * 4 + 2] + mrgf[mbase + mt2 * 16 + g * 4 + 2]) * inv;
        float o3 = (ot[mt2][g * 4 + 3] + mrgf[mbase + mt2 * 16 + g * 4 + 3]) * inv;
        uint2 pkk;
        pkk.x = (u32)f2bf(o0) | ((u32)f2bf(o1) << 16);
        pkk.y = (u32)f2bf(o2) | ((u32)f2bf(o3) << 16);
        *(uint2*)(ctx + base + mt2 * 32 + g * 8 + 4 * h) = pkk;
      }
    }
  }
}

// ---------------- LayerNorm in place on d_out ----------------
__global__ __launch_bounds__(256) void ln_kernel(
    float* __restrict__ x, const float* __restrict__ gamma, const float* __restrict__ beta) {
  __shared__ float red[8];
  const int tid = threadIdx.x;
  const long row = blockIdx.x;
  float4 v = *(const float4*)(x + row * EMBED + tid * 4);
  float s = v.x + v.y + v.z + v.w;
  float sq = v.x * v.x + v.y * v.y + v.z * v.z + v.w * v.w;
#pragma unroll
  for (int off = 1; off < 64; off <<= 1) {
    s += __shfl_xor(s, off);
    sq += __shfl_xor(sq, off);
  }
  if ((tid & 63) == 0) {
    red[(tid >> 6) * 2] = s;
    red[(tid >> 6) * 2 + 1] = sq;
  }
  __syncthreads();
  s = red[0] + red[2] + red[4] + red[6];
  sq = red[1] + red[3] + red[5] + red[7];
  float mu = s * (1.f / EMBED);
  float var = sq * (1.f / EMBED) - mu * mu;
  float rstd = rsqrtf(var + 1e-5f);
  float4 g = *(const float4*)(gamma + tid * 4);
  float4 bt = *(const float4*)(beta + tid * 4);
  float4 ov;
  ov.x = (v.x - mu) * rstd * g.x + bt.x;
  ov.y = (v.y - mu) * rstd * g.y + bt.y;
  ov.z = (v.z - mu) * rstd * g.z + bt.z;
  ov.w = (v.w - mu) * rstd * g.w + bt.w;
  *(float4*)(x + row * EMBED + tid * 4) = ov;
}

extern "C" void kernel_launch(void* const* d_in, const int* in_sizes, int n_in,
                              void* d_out, int out_size, void* d_ws, size_t ws_size,
                              hipStream_t stream) {
  const float* q     = (const float*)d_in[0];
  const float* kv    = (const float*)d_in[1];
  // d_in[2] = prompt_size (0, unused)
  const float* Wq    = (const float*)d_in[3];
  const float* bq    = (const float*)d_in[4];
  const float* Wk    = (const float*)d_in[5];
  const float* bk    = (const float*)d_in[6];
  const float* Wv    = (const float*)d_in[7];
  const float* bv    = (const float*)d_in[8];
  const float* Wo    = (const float*)d_in[9];
  const float* bo    = (const float*)d_in[10];
  const float* gamma = (const float*)d_in[11];
  const float* beta  = (const float*)d_in[12];

  char* ws = (char*)d_ws;
  u16* qb  = (u16*)(ws + (0l  << 20));  // 8 MB
  u16* kvb = (u16*)(ws + (8l  << 20));  // 8 MB
  u16* wqb = (u16*)(ws + (16l << 20));  // 2 MB
  u16* wkb = (u16*)(ws + (18l << 20));
  u16* wvb = (u16*)(ws + (20l << 20));
  u16* wob = (u16*)(ws + (22l << 20));
  u16* Qh  = (u16*)(ws + (24l << 20));  // 8 MB [bh][L][64] (pre-scaled by QSCALE)
  u16* Kh  = (u16*)(ws + (32l << 20));  // 8 MB [bh][L][64]
  u16* Vt  = (u16*)(ws + (40l << 20));  // 8 MB [bh][64][L]
  u16* ctx = (u16*)(ws + (48l << 20));  // 8 MB [B][L][E]   (total 56 MB)
  float* out = (float*)d_out;

  cast_kernel<<<6144, 256, 0, stream>>>(q, kv, Wq, Wk, Wv, Wo, qb, kvb, wqb, wkb, wvb, wob);
  qkv_kernel<<<dim3(64, 8, 3), 256, 0, stream>>>(qb, kvb, wqb, wkb, wvb, bq, bk, bv, Qh, Kh, Vt);
  attn_kernel<<<512, 512, 0, stream>>>(Qh, Kh, Vt, ctx);
  oproj_kernel<<<dim3(64, 8), 256, 0, stream>>>(ctx, wob, bo, q, out);
  ln_kernel<<<4096, 256, 0, stream>>>(out, gamma, beta);
}